// Round 5
// baseline (273.889 us; speedup 1.0000x reference)
//
#include <hip/hip_runtime.h>

// MAB block, MFMA bf16, round 5: register-double-buffered flash attention
// (32-key tiles, prefetch t+1 before compute t), XCD-swizzled block mapping,
// W-frag-hoisted GEMMs, 8-wave fused FFN2+residual+LN.

typedef float fx4 __attribute__((ext_vector_type(4)));
typedef short short8 __attribute__((ext_vector_type(8)));

#define BB  4
#define NN  2048
#define DD  256
#define HH  4
#define DHH 64

__device__ __forceinline__ float bf2f(unsigned short u) {
    union { unsigned int i; float f; } v; v.i = ((unsigned int)u) << 16; return v.f;
}
__device__ __forceinline__ unsigned short f2bf(float f) {
    union { float f; unsigned int i; } v; v.f = f;
    unsigned int r = v.i + 0x7FFF + ((v.i >> 16) & 1);   // RNE
    return (unsigned short)(r >> 16);
}
__device__ __forceinline__ unsigned int fbits(float f) {
    union { float f; unsigned int i; } v; v.f = f; return v.i;
}

// ---------------------------------------------------------------------------
// Weight prep: WT[n][k] = bf16(W[k][n]) for the 5 weight matrices (256x256).
// ---------------------------------------------------------------------------
__global__ __launch_bounds__(256) void wt_prep(
        const float* __restrict__ w0, const float* __restrict__ w1,
        const float* __restrict__ w2, const float* __restrict__ w3,
        const float* __restrict__ w4, unsigned short* __restrict__ dst) {
    __shared__ unsigned short T[64 * 73];
    const int tid = threadIdx.x;
    const int z = blockIdx.z;
    const float* W = (z == 0) ? w0 : (z == 1) ? w1 : (z == 2) ? w2 : (z == 3) ? w3 : w4;
    unsigned short* WT = dst + z * 65536;
    const int nb = blockIdx.x * 64, kb = blockIdx.y * 64;
    {
        int kl = tid >> 2, c0 = (tid & 3) * 16;
        const float* src = W + (size_t)(kb + kl) * DD + nb + c0;
#pragma unroll
        for (int i = 0; i < 16; ++i) T[kl * 73 + c0 + i] = f2bf(src[i]);
    }
    __syncthreads();
    {
        int nl = tid >> 2, k0 = (tid & 3) * 16;
        short8 o0, o1;
#pragma unroll
        for (int i = 0; i < 8; ++i) {
            o0[i] = (short)T[(k0 + i) * 73 + nl];
            o1[i] = (short)T[(k0 + 8 + i) * 73 + nl];
        }
        short8* d = (short8*)(WT + (size_t)(nb + nl) * DD + kb + k0);
        d[0] = o0; d[1] = o1;
    }
}

// ---------------------------------------------------------------------------
// V transpose: VT[(b*4+h)*64 + d][key] = Vp[b*2048+key][h*64+d]. grid(128,4).
// ---------------------------------------------------------------------------
__global__ __launch_bounds__(256) void vt_prep(
        const unsigned short* __restrict__ Vp, unsigned short* __restrict__ VT) {
    __shared__ unsigned short T[64 * 73];
    const int tid = threadIdx.x;
    const int hb = blockIdx.y;
    const int b = blockIdx.x >> 5;
    const int keyb = (blockIdx.x & 31) * 64;
    {
        int kl = tid >> 2, c0 = (tid & 3) * 16;
        const short8* src = (const short8*)(Vp + (size_t)(b * NN + keyb + kl) * DD + hb * DHH + c0);
        short8 v0 = src[0], v1 = src[1];
#pragma unroll
        for (int i = 0; i < 8; ++i) {
            T[kl * 73 + c0 + i]     = (unsigned short)v0[i];
            T[kl * 73 + c0 + 8 + i] = (unsigned short)v1[i];
        }
    }
    __syncthreads();
    {
        int dl = tid >> 2, k0 = (tid & 3) * 16;
        short8 o0, o1;
#pragma unroll
        for (int i = 0; i < 8; ++i) {
            o0[i] = (short)T[(k0 + i) * 73 + dl];
            o1[i] = (short)T[(k0 + 8 + i) * 73 + dl];
        }
        short8* d = (short8*)(VT + (size_t)((b * HH + hb) * DHH + dl) * NN + keyb + k0);
        d[0] = o0; d[1] = o1;
    }
}

// ---------------------------------------------------------------------------
// MFMA GEMM, col-split: block = 16 rows x 128 cols (4 waves, wave = 16x32).
// W-frags hoisted into registers BEFORE the A-staging barrier.
// AIN: 0 fp32 A, 1 bf16 A.  EP: 0 bias->bf16, 1 relu->bf16.
// ---------------------------------------------------------------------------
template<int AIN, int EP>
__global__ __launch_bounds__(256, 4) void gemm_mfma(
        const void* __restrict__ Ain, const unsigned short* __restrict__ WT,
        const float* __restrict__ bias, void* __restrict__ Cout) {
    __shared__ unsigned short As[16 * 264];
    const int tid = threadIdx.x;
    const int lane = tid & 63, w = tid >> 6;
    const int l15 = lane & 15, quad = lane >> 4;
    const int r0 = (blockIdx.x >> 1) * 16;
    const int c0w = (blockIdx.x & 1) * 128 + w * 32;
    // hoisted W-frag loads (independent of LDS staging)
    short8 wf[8][2];
#pragma unroll
    for (int kc = 0; kc < 8; ++kc)
#pragma unroll
        for (int dt = 0; dt < 2; ++dt)
            wf[kc][dt] = *(const short8*)(WT + (size_t)(c0w + dt * 16 + l15) * DD + kc * 32 + 8 * quad);
    float bv[2];
#pragma unroll
    for (int dt = 0; dt < 2; ++dt) bv[dt] = bias[c0w + dt * 16 + l15];
    {   // stage A tile (16 x 256) as bf16
        int row = tid >> 4, c0 = (tid & 15) * 16;
        short8 o0, o1;
        if (AIN == 0) {
            const fx4* s4 = (const fx4*)((const float*)Ain + (size_t)(r0 + row) * DD + c0);
            fx4 v0 = s4[0], v1 = s4[1], v2 = s4[2], v3 = s4[3];
#pragma unroll
            for (int i = 0; i < 4; ++i) {
                o0[i]     = (short)f2bf(v0[i]); o0[i + 4] = (short)f2bf(v1[i]);
                o1[i]     = (short)f2bf(v2[i]); o1[i + 4] = (short)f2bf(v3[i]);
            }
        } else {
            const short8* s8 = (const short8*)((const unsigned short*)Ain + (size_t)(r0 + row) * DD + c0);
            o0 = s8[0]; o1 = s8[1];
        }
        short8* d = (short8*)(As + row * 264 + c0);
        d[0] = o0; d[1] = o1;
    }
    __syncthreads();
    fx4 acc[2];
#pragma unroll
    for (int i = 0; i < 2; ++i) acc[i] = (fx4){0.f, 0.f, 0.f, 0.f};
#pragma unroll
    for (int kc = 0; kc < 8; ++kc) {
        short8 a = *(const short8*)(As + l15 * 264 + kc * 32 + 8 * quad);
#pragma unroll
        for (int dt = 0; dt < 2; ++dt)
            acc[dt] = __builtin_amdgcn_mfma_f32_16x16x32_bf16(a, wf[kc][dt], acc[dt], 0, 0, 0);
    }
#pragma unroll
    for (int r = 0; r < 4; ++r) {
        const size_t grow = r0 + 4 * quad + r;
#pragma unroll
        for (int dt = 0; dt < 2; ++dt) {
            const int col = c0w + dt * 16 + l15;
            float v = acc[dt][r] + bv[dt];
            if (EP == 1) v = fmaxf(v, 0.0f);
            ((unsigned short*)Cout)[grow * DD + col] = f2bf(v);
        }
    }
}

// ---------------------------------------------------------------------------
// FFN2 + residual + LayerNorm fused: out = LN(R + A@W2 + b2), fp32 out.
// Block = 16 rows x 256 cols, 8 waves (wave = 16x32), W-frags hoisted.
// ---------------------------------------------------------------------------
__global__ __launch_bounds__(512, 4) void gemm_ffn2_ln(
        const unsigned short* __restrict__ Ain, const unsigned short* __restrict__ WT,
        const float* __restrict__ bias, const float* __restrict__ R,
        const float* __restrict__ g, const float* __restrict__ be,
        float* __restrict__ out) {
    __shared__ unsigned short As[16 * 264];
    __shared__ float lnb[2][8][16];
    const int tid = threadIdx.x;
    const int lane = tid & 63, w = tid >> 6;          // w in 0..7
    const int l15 = lane & 15, quad = lane >> 4;
    const int r0 = blockIdx.x * 16;
    const int c0w = w * 32;
    short8 wf[8][2];
#pragma unroll
    for (int kc = 0; kc < 8; ++kc)
#pragma unroll
        for (int dt = 0; dt < 2; ++dt)
            wf[kc][dt] = *(const short8*)(WT + (size_t)(c0w + dt * 16 + l15) * DD + kc * 32 + 8 * quad);
    float bv[2], gv[2], ev[2];
#pragma unroll
    for (int dt = 0; dt < 2; ++dt) {
        int col = c0w + dt * 16 + l15;
        bv[dt] = bias[col]; gv[dt] = g[col]; ev[dt] = be[col];
    }
    {   // stage A: 512 threads x 16B
        int row = tid >> 5, c0 = (tid & 31) * 8;
        *(short8*)(As + row * 264 + c0) = *(const short8*)(Ain + (size_t)(r0 + row) * DD + c0);
    }
    __syncthreads();
    fx4 acc[2];
#pragma unroll
    for (int i = 0; i < 2; ++i) acc[i] = (fx4){0.f, 0.f, 0.f, 0.f};
#pragma unroll
    for (int kc = 0; kc < 8; ++kc) {
        short8 a = *(const short8*)(As + l15 * 264 + kc * 32 + 8 * quad);
#pragma unroll
        for (int dt = 0; dt < 2; ++dt)
            acc[dt] = __builtin_amdgcn_mfma_f32_16x16x32_bf16(a, wf[kc][dt], acc[dt], 0, 0, 0);
    }
    float v[4][2], p1[4], p2[4];
#pragma unroll
    for (int r = 0; r < 4; ++r) {
        p1[r] = 0.f; p2[r] = 0.f;
        const size_t grow = r0 + 4 * quad + r;
#pragma unroll
        for (int dt = 0; dt < 2; ++dt) {
            float x = acc[dt][r] + bv[dt] + R[grow * DD + c0w + dt * 16 + l15];
            v[r][dt] = x; p1[r] += x; p2[r] += x * x;
        }
    }
#pragma unroll
    for (int r = 0; r < 4; ++r) {
#pragma unroll
        for (int off = 1; off <= 8; off <<= 1) {
            p1[r] += __shfl_xor(p1[r], off);
            p2[r] += __shfl_xor(p2[r], off);
        }
    }
    if (l15 == 0) {
#pragma unroll
        for (int r = 0; r < 4; ++r) {
            lnb[0][w][4 * quad + r] = p1[r];
            lnb[1][w][4 * quad + r] = p2[r];
        }
    }
    __syncthreads();
#pragma unroll
    for (int r = 0; r < 4; ++r) {
        const int row = 4 * quad + r;
        float s1 = 0.f, s2 = 0.f;
#pragma unroll
        for (int ww = 0; ww < 8; ++ww) { s1 += lnb[0][ww][row]; s2 += lnb[1][ww][row]; }
        float mean = s1 * (1.0f / 256.0f);
        float var  = s2 * (1.0f / 256.0f) - mean * mean;
        float rstd = rsqrtf(var + 1e-5f);
        const size_t grow = r0 + row;
#pragma unroll
        for (int dt = 0; dt < 2; ++dt)
            out[grow * DD + c0w + dt * 16 + l15] = (v[r][dt] - mean) * rstd * gv[dt] + ev[dt];
    }
}

// ---------------------------------------------------------------------------
// Flash attention, S^T form, k-split-2, register double-buffered 32-key tiles.
// Block = 32 q-rows, 4 waves: wave w -> q-subtile (w&1)*16, K-half (w>>1).
// XCD-swizzled block decode: 2 (b,h) pairs per XCD -> K/V L2-resident.
// ---------------------------------------------------------------------------
__global__ __launch_bounds__(256, 4) void attn_mfma(
        const unsigned short* __restrict__ Qp, const unsigned short* __restrict__ Kp,
        const unsigned short* __restrict__ VT, float* __restrict__ Opre) {
    __shared__ unsigned short plds[4 * 16 * 40];   // per-wave P (pitch 40 u16)
    __shared__ float macc[2 * 16 * 65];            // merge area (pitch 65)
    __shared__ float mstat[2][4][16];              // [m/l][wave][q]
    const int tid = threadIdx.x;
    const int lane = tid & 63, w = tid >> 6;
    const int l15 = lane & 15, quad = lane >> 4;
    const int qs = w & 1, kh = w >> 1;
    const int gb = blockIdx.x;
    const int bh = ((gb & 7) << 1) | ((gb >> 9) & 1);   // XCD-locality swizzle
    const int qc = (gb >> 3) & 63;
    const int h  = bh & 3;
    const int b  = bh >> 2;
    const int qrow = qc * 32 + qs * 16;

    short8 aq0, aq1;
    {
        const unsigned short* qptr = Qp + ((size_t)(b * NN + qrow + l15) * DD + h * DHH + 8 * quad);
        aq0 = *(const short8*)qptr;
        aq1 = *(const short8*)(qptr + 32);
    }
    fx4 od[4];
#pragma unroll
    for (int i = 0; i < 4; ++i) od[i] = (fx4){0.f, 0.f, 0.f, 0.f};
    float m = -1e30f, l = 0.0f;

    unsigned short* pl = plds + w * (16 * 40);
    const unsigned short* kbase = Kp + ((size_t)(b * NN) * DD + h * DHH + 8 * quad);
    const unsigned short* vbase = VT + ((size_t)((b * HH + h) * DHH)) * NN + 8 * quad;

    auto pref = [&](short8* kf, short8* vf, int t) {
        const int kt = kh * 1024 + t * 32;
        const unsigned short* kp0 = kbase + (size_t)(kt + l15) * DD;
        kf[0] = *(const short8*)kp0;
        kf[1] = *(const short8*)(kp0 + 32);
        const unsigned short* kp1 = kbase + (size_t)(kt + 16 + l15) * DD;
        kf[2] = *(const short8*)kp1;
        kf[3] = *(const short8*)(kp1 + 32);
#pragma unroll
        for (int dt = 0; dt < 4; ++dt)
            vf[dt] = *(const short8*)(vbase + (size_t)(dt * 16 + l15) * NN + kt);
    };

    auto body = [&](short8* ck, short8* cv, short8* nk, short8* nv, int t) {
        const int tn = (t + 1 < 32) ? t + 1 : 31;
        pref(nk, nv, tn);                       // issue next-tile loads first
        const fx4 z = (fx4){0.f, 0.f, 0.f, 0.f};
        fx4 s0 = __builtin_amdgcn_mfma_f32_16x16x32_bf16(ck[0], aq0, z, 0, 0, 0);
        s0     = __builtin_amdgcn_mfma_f32_16x16x32_bf16(ck[1], aq1, s0, 0, 0, 0);
        fx4 s1 = __builtin_amdgcn_mfma_f32_16x16x32_bf16(ck[2], aq0, z, 0, 0, 0);
        s1     = __builtin_amdgcn_mfma_f32_16x16x32_bf16(ck[3], aq1, s1, 0, 0, 0);
        s0 *= 0.125f; s1 *= 0.125f;
        float tm = fmaxf(fmaxf(fmaxf(s0[0], s0[1]), fmaxf(s0[2], s0[3])),
                         fmaxf(fmaxf(s1[0], s1[1]), fmaxf(s1[2], s1[3])));
        tm = fmaxf(tm, __shfl_xor(tm, 16));
        tm = fmaxf(tm, __shfl_xor(tm, 32));
        float mn = fmaxf(m, tm);
        float al = __expf(m - mn);
        m = mn;
        float tl = 0.f;
#pragma unroll
        for (int i = 0; i < 4; ++i) {
            s0[i] = __expf(s0[i] - m); tl += s0[i];
            s1[i] = __expf(s1[i] - m); tl += s1[i];
        }
        tl += __shfl_xor(tl, 16);
        tl += __shfl_xor(tl, 32);
        l = l * al + tl;
        {
            unsigned int d0 = ((fbits(s0[0]) + 0x8000u) >> 16) | ((fbits(s0[1]) + 0x8000u) & 0xFFFF0000u);
            unsigned int d1 = ((fbits(s0[2]) + 0x8000u) >> 16) | ((fbits(s0[3]) + 0x8000u) & 0xFFFF0000u);
            *(unsigned long long*)(pl + l15 * 40 + 4 * quad) =
                (unsigned long long)d0 | ((unsigned long long)d1 << 32);
            d0 = ((fbits(s1[0]) + 0x8000u) >> 16) | ((fbits(s1[1]) + 0x8000u) & 0xFFFF0000u);
            d1 = ((fbits(s1[2]) + 0x8000u) >> 16) | ((fbits(s1[3]) + 0x8000u) & 0xFFFF0000u);
            *(unsigned long long*)(pl + l15 * 40 + 16 + 4 * quad) =
                (unsigned long long)d0 | ((unsigned long long)d1 << 32);
        }
        float ar[4];
#pragma unroll
        for (int r = 0; r < 4; ++r) ar[r] = __shfl(al, 4 * quad + r);
#pragma unroll
        for (int dt = 0; dt < 4; ++dt)
#pragma unroll
            for (int r = 0; r < 4; ++r) od[dt][r] *= ar[r];
        short8 ap = *(const short8*)(pl + l15 * 40 + 8 * quad);
#pragma unroll
        for (int dt = 0; dt < 4; ++dt)
            od[dt] = __builtin_amdgcn_mfma_f32_16x16x32_bf16(ap, cv[dt], od[dt], 0, 0, 0);
    };

    short8 ka[4], va[4], kb[4], vb[4];
    pref(ka, va, 0);
    for (int tt = 0; tt < 16; ++tt) {
        body(ka, va, kb, vb, 2 * tt);
        body(kb, vb, ka, va, 2 * tt + 1);
    }
    // ---- merge the two K-halves ----
    if (quad == 0) { mstat[0][w][l15] = m; mstat[1][w][l15] = l; }
    __syncthreads();
    {
        const int pw = w ^ 2;
        float m2 = mstat[0][pw][l15], l2 = mstat[1][pw][l15];
        float M = fmaxf(m, m2);
        float a  = __expf(m - M);
        float a2 = __expf(m2 - M);
        float L = a * l + a2 * l2;
        float c = a / L;
        float cr[4];
#pragma unroll
        for (int r = 0; r < 4; ++r) cr[r] = __shfl(c, 4 * quad + r);
#pragma unroll
        for (int dt = 0; dt < 4; ++dt)
#pragma unroll
            for (int r = 0; r < 4; ++r) od[dt][r] *= cr[r];
    }
    if (kh == 0) {
#pragma unroll
        for (int r = 0; r < 4; ++r)
#pragma unroll
            for (int dt = 0; dt < 4; ++dt)
                macc[(qs * 16 + 4 * quad + r) * 65 + dt * 16 + l15] = od[dt][r];
    }
    __syncthreads();
    if (kh == 1) {
#pragma unroll
        for (int r = 0; r < 4; ++r) {
            const size_t grow = (size_t)(b * NN) + qrow + 4 * quad + r;
#pragma unroll
            for (int dt = 0; dt < 4; ++dt) {
                const int col = h * DHH + dt * 16 + l15;
                float val = od[dt][r] + macc[(qs * 16 + 4 * quad + r) * 65 + dt * 16 + l15]
                          + bf2f(Qp[grow * DD + col]);
                Opre[grow * DD + col] = val;
            }
        }
    }
}

// row LayerNorm: Y = LN(X)*g+be (fp32)
__global__ __launch_bounds__(64) void ln_rows(
        const float* __restrict__ X, const float* __restrict__ g,
        const float* __restrict__ be, float* __restrict__ Y) {
    const int lane = threadIdx.x;
    const size_t row = blockIdx.x;
    fx4 v = ((const fx4*)(X + row * DD))[lane];
    float s1 = v[0]+v[1]+v[2]+v[3];
    float s2 = v[0]*v[0]+v[1]*v[1]+v[2]*v[2]+v[3]*v[3];
#pragma unroll
    for (int off = 32; off >= 1; off >>= 1) {
        s1 += __shfl_xor(s1, off); s2 += __shfl_xor(s2, off);
    }
    float mean = s1 * (1.0f/256.0f);
    float var  = s2 * (1.0f/256.0f) - mean * mean;
    float rstd = rsqrtf(var + 1e-5f);
    fx4 gv = ((const fx4*)g)[lane];
    fx4 ev = ((const fx4*)be)[lane];
    fx4 o;
#pragma unroll
    for (int i = 0; i < 4; ++i) o[i] = (v[i]-mean)*rstd*gv[i] + ev[i];
    ((fx4*)(Y + row * DD))[lane] = o;
}

extern "C" void kernel_launch(void* const* d_in, const int* in_sizes, int n_in,
                              void* d_out, int out_size, void* d_ws, size_t ws_size,
                              hipStream_t stream) {
    (void)in_sizes; (void)n_in; (void)out_size; (void)ws_size;
    const float* Q     = (const float*)d_in[0];
    const float* K     = (const float*)d_in[1];
    const float* Wq    = (const float*)d_in[2];
    const float* bq    = (const float*)d_in[3];
    const float* Wk    = (const float*)d_in[4];
    const float* bk    = (const float*)d_in[5];
    const float* Wv    = (const float*)d_in[6];
    const float* bv    = (const float*)d_in[7];
    const float* W1    = (const float*)d_in[8];
    const float* b1    = (const float*)d_in[9];
    const float* W2    = (const float*)d_in[10];
    const float* b2    = (const float*)d_in[11];
    const float* g0    = (const float*)d_in[12];
    const float* beta0 = (const float*)d_in[13];
    const float* g1    = (const float*)d_in[14];
    const float* beta1 = (const float*)d_in[15];

    // Workspace: [0,4)Mi Qp bf16 (later H1 bf16); [4,8)Mi Kp; [8,12)Mi Vp;
    // [12,16)Mi VT; [16,24)Mi Opre f32; [24,32)Mi O f32; [32Mi,+640K) WT x5
    char* ws = (char*)d_ws;
    unsigned short* Qp  = (unsigned short*)(ws);
    unsigned short* Kp  = (unsigned short*)(ws + (4u  << 20));
    unsigned short* Vp  = (unsigned short*)(ws + (8u  << 20));
    unsigned short* VT  = (unsigned short*)(ws + (12u << 20));
    float*          Opre= (float*)(ws + (16u << 20));
    float*          O   = (float*)(ws + (24u << 20));
    unsigned short* WT5 = (unsigned short*)(ws + (32u << 20));
    unsigned short* H1  = Qp;
    float*          out = (float*)d_out;

    const unsigned short* WTq = WT5;
    const unsigned short* WTk = WT5 + 65536;
    const unsigned short* WTv = WT5 + 2 * 65536;
    const unsigned short* WT1 = WT5 + 3 * 65536;
    const unsigned short* WT2 = WT5 + 4 * 65536;

    const int M = BB * NN;                        // 8192 rows

    wt_prep<<<dim3(4, 4, 5), 256, 0, stream>>>(Wq, Wk, Wv, W1, W2, WT5);
    gemm_mfma<0, 0><<<M / 8, 256, 0, stream>>>(Q, WTq, bq, Qp);
    gemm_mfma<0, 0><<<M / 8, 256, 0, stream>>>(K, WTk, bk, Kp);
    gemm_mfma<0, 0><<<M / 8, 256, 0, stream>>>(K, WTv, bv, Vp);
    vt_prep<<<dim3(128, 4), 256, 0, stream>>>(Vp, VT);
    attn_mfma<<<BB * HH * (NN / 32), 256, 0, stream>>>(Qp, Kp, VT, Opre);
    ln_rows<<<M, 64, 0, stream>>>(Opre, g0, beta0, O);
    gemm_mfma<0, 1><<<M / 8, 256, 0, stream>>>(O, WT1, b1, H1);
    gemm_ffn2_ln<<<M / 16, 512, 0, stream>>>(H1, WT2, b2, O, g1, beta1, out);
}

// Round 6
// 261.971 us; speedup vs baseline: 1.0455x; 1.0455x over previous
//
#include <hip/hip_runtime.h>

// MAB block, MFMA bf16, round 6: O^T-form flash attention with no-max softmax
// (per-thread stats, zero shuffles in K-loop), XOR-swizzled P exchange,
// fused QKV projections, 32-row GEMM tiles.

typedef float fx4 __attribute__((ext_vector_type(4)));
typedef short short8 __attribute__((ext_vector_type(8)));
typedef short shortx4 __attribute__((ext_vector_type(4)));
typedef unsigned int uint2v __attribute__((ext_vector_type(2)));

#define BB  4
#define NN  2048
#define DD  256
#define HH  4
#define DHH 64

__device__ __forceinline__ float bf2f(unsigned short u) {
    union { unsigned int i; float f; } v; v.i = ((unsigned int)u) << 16; return v.f;
}
__device__ __forceinline__ unsigned short f2bf(float f) {
    union { float f; unsigned int i; } v; v.f = f;
    unsigned int r = v.i + 0x7FFF + ((v.i >> 16) & 1);   // RNE
    return (unsigned short)(r >> 16);
}
__device__ __forceinline__ unsigned int fbits(float f) {
    union { float f; unsigned int i; } v; v.f = f; return v.i;
}
__device__ __forceinline__ unsigned int packbf(float lo, float hi) {
    unsigned int a = fbits(lo), b = fbits(hi);
    a = (a + 0x7FFF + ((a >> 16) & 1)) >> 16;
    b = (b + 0x7FFF + ((b >> 16) & 1)) & 0xFFFF0000u;
    return a | b;
}

// ---------------------------------------------------------------------------
// Weight prep: WT[n][k] = bf16(W[k][n]) for the 5 weight matrices (256x256).
// ---------------------------------------------------------------------------
__global__ __launch_bounds__(256) void wt_prep(
        const float* __restrict__ w0, const float* __restrict__ w1,
        const float* __restrict__ w2, const float* __restrict__ w3,
        const float* __restrict__ w4, unsigned short* __restrict__ dst) {
    __shared__ unsigned short T[64 * 73];
    const int tid = threadIdx.x;
    const int z = blockIdx.z;
    const float* W = (z == 0) ? w0 : (z == 1) ? w1 : (z == 2) ? w2 : (z == 3) ? w3 : w4;
    unsigned short* WT = dst + z * 65536;
    const int nb = blockIdx.x * 64, kb = blockIdx.y * 64;
    {
        int kl = tid >> 2, c0 = (tid & 3) * 16;
        const float* src = W + (size_t)(kb + kl) * DD + nb + c0;
#pragma unroll
        for (int i = 0; i < 16; ++i) T[kl * 73 + c0 + i] = f2bf(src[i]);
    }
    __syncthreads();
    {
        int nl = tid >> 2, k0 = (tid & 3) * 16;
        short8 o0, o1;
#pragma unroll
        for (int i = 0; i < 8; ++i) {
            o0[i] = (short)T[(k0 + i) * 73 + nl];
            o1[i] = (short)T[(k0 + 8 + i) * 73 + nl];
        }
        short8* d = (short8*)(WT + (size_t)(nb + nl) * DD + kb + k0);
        d[0] = o0; d[1] = o1;
    }
}

// ---------------------------------------------------------------------------
// V transpose: VT[(b*4+h)*64 + d][key] = Vp[b*2048+key][h*64+d]. grid(128,4).
// ---------------------------------------------------------------------------
__global__ __launch_bounds__(256) void vt_prep(
        const unsigned short* __restrict__ Vp, unsigned short* __restrict__ VT) {
    __shared__ unsigned short T[64 * 73];
    const int tid = threadIdx.x;
    const int hb = blockIdx.y;
    const int b = blockIdx.x >> 5;
    const int keyb = (blockIdx.x & 31) * 64;
    {
        int kl = tid >> 2, c0 = (tid & 3) * 16;
        const short8* src = (const short8*)(Vp + (size_t)(b * NN + keyb + kl) * DD + hb * DHH + c0);
        short8 v0 = src[0], v1 = src[1];
#pragma unroll
        for (int i = 0; i < 8; ++i) {
            T[kl * 73 + c0 + i]     = (unsigned short)v0[i];
            T[kl * 73 + c0 + 8 + i] = (unsigned short)v1[i];
        }
    }
    __syncthreads();
    {
        int dl = tid >> 2, k0 = (tid & 3) * 16;
        short8 o0, o1;
#pragma unroll
        for (int i = 0; i < 8; ++i) {
            o0[i] = (short)T[(k0 + i) * 73 + dl];
            o1[i] = (short)T[(k0 + 8 + i) * 73 + dl];
        }
        short8* d = (short8*)(VT + (size_t)((b * HH + hb) * DHH + dl) * NN + keyb + k0);
        d[0] = o0; d[1] = o1;
    }
}

// ---------------------------------------------------------------------------
// 32-row GEMM body: C[r0..r0+32, c-half] = A @ W + bias. 4 waves, wave =
// 32 rows x 32 cols. W-frags hoisted. AIN: 0 fp32 A, 1 bf16 A.
// EP: 0 bias->bf16, 1 relu->bf16.
// ---------------------------------------------------------------------------
template<int AIN, int EP>
__device__ __forceinline__ void gemm32_body(
        const void* __restrict__ Ain, const unsigned short* __restrict__ WT,
        const float* __restrict__ bias, void* __restrict__ Cout, int bx) {
    __shared__ unsigned short As[32 * 264];
    const int tid = threadIdx.x;
    const int lane = tid & 63, w = tid >> 6;
    const int l15 = lane & 15, quad = lane >> 4;
    const int r0 = (bx >> 1) * 32;
    const int c0w = (bx & 1) * 128 + w * 32;
    short8 wf[8][2];
#pragma unroll
    for (int kc = 0; kc < 8; ++kc)
#pragma unroll
        for (int dt = 0; dt < 2; ++dt)
            wf[kc][dt] = *(const short8*)(WT + (size_t)(c0w + dt * 16 + l15) * DD + kc * 32 + 8 * quad);
    float bv[2];
#pragma unroll
    for (int dt = 0; dt < 2; ++dt) bv[dt] = bias[c0w + dt * 16 + l15];
    {   // stage A tile (32 x 256) as bf16; thread: 32 elems
        int row = tid >> 3, c0 = (tid & 7) * 32;
        short8 o[4];
        if (AIN == 0) {
            const fx4* s4 = (const fx4*)((const float*)Ain + (size_t)(r0 + row) * DD + c0);
#pragma unroll
            for (int j = 0; j < 4; ++j) {
                fx4 v0 = s4[2 * j], v1 = s4[2 * j + 1];
#pragma unroll
                for (int i = 0; i < 4; ++i) {
                    o[j][i]     = (short)f2bf(v0[i]);
                    o[j][i + 4] = (short)f2bf(v1[i]);
                }
            }
        } else {
            const short8* s8 = (const short8*)((const unsigned short*)Ain + (size_t)(r0 + row) * DD + c0);
#pragma unroll
            for (int j = 0; j < 4; ++j) o[j] = s8[j];
        }
        short8* d = (short8*)(As + row * 264 + c0);
#pragma unroll
        for (int j = 0; j < 4; ++j) d[j] = o[j];
    }
    __syncthreads();
    fx4 acc[2][2];
#pragma unroll
    for (int mt = 0; mt < 2; ++mt)
#pragma unroll
        for (int dt = 0; dt < 2; ++dt) acc[mt][dt] = (fx4){0.f, 0.f, 0.f, 0.f};
#pragma unroll
    for (int kc = 0; kc < 8; ++kc) {
        short8 a0 = *(const short8*)(As + l15 * 264 + kc * 32 + 8 * quad);
        short8 a1 = *(const short8*)(As + (16 + l15) * 264 + kc * 32 + 8 * quad);
#pragma unroll
        for (int dt = 0; dt < 2; ++dt) {
            acc[0][dt] = __builtin_amdgcn_mfma_f32_16x16x32_bf16(a0, wf[kc][dt], acc[0][dt], 0, 0, 0);
            acc[1][dt] = __builtin_amdgcn_mfma_f32_16x16x32_bf16(a1, wf[kc][dt], acc[1][dt], 0, 0, 0);
        }
    }
#pragma unroll
    for (int mt = 0; mt < 2; ++mt)
#pragma unroll
        for (int r = 0; r < 4; ++r) {
            const size_t grow = r0 + mt * 16 + 4 * quad + r;
#pragma unroll
            for (int dt = 0; dt < 2; ++dt) {
                float v = acc[mt][dt][r] + bv[dt];
                if (EP == 1) v = fmaxf(v, 0.0f);
                ((unsigned short*)Cout)[grow * DD + c0w + dt * 16 + l15] = f2bf(v);
            }
        }
}

// Fused QKV projections: grid (512, 3); y selects {Q->Qp, K->Kp, K->Vp}.
__global__ __launch_bounds__(256, 4) void qkv_mfma(
        const float* __restrict__ Q, const float* __restrict__ K,
        const unsigned short* __restrict__ WT5,
        const float* __restrict__ bq, const float* __restrict__ bk,
        const float* __restrict__ bv,
        unsigned short* __restrict__ Qp, unsigned short* __restrict__ Kp,
        unsigned short* __restrict__ Vp) {
    const int z = blockIdx.y;
    const float* A = (z == 0) ? Q : K;
    const float* bias = (z == 0) ? bq : (z == 1) ? bk : bv;
    unsigned short* C = (z == 0) ? Qp : (z == 1) ? Kp : Vp;
    gemm32_body<0, 0>(A, WT5 + z * 65536, bias, C, blockIdx.x);
}

// FFN1: H1 = relu(O @ W1 + b1), O fp32.
__global__ __launch_bounds__(256, 4) void ffn1_mfma(
        const float* __restrict__ O, const unsigned short* __restrict__ WT1,
        const float* __restrict__ b1, unsigned short* __restrict__ H1) {
    gemm32_body<0, 1>(O, WT1, b1, H1, blockIdx.x);
}

// ---------------------------------------------------------------------------
// FFN2 + residual + LayerNorm fused: out = LN(R + A@W2 + b2), fp32 out.
// Block = 16 rows x 256 cols, 8 waves (wave = 16x32), W-frags hoisted.
// ---------------------------------------------------------------------------
__global__ __launch_bounds__(512, 4) void gemm_ffn2_ln(
        const unsigned short* __restrict__ Ain, const unsigned short* __restrict__ WT,
        const float* __restrict__ bias, const float* __restrict__ R,
        const float* __restrict__ g, const float* __restrict__ be,
        float* __restrict__ out) {
    __shared__ unsigned short As[16 * 264];
    __shared__ float lnb[2][8][16];
    const int tid = threadIdx.x;
    const int lane = tid & 63, w = tid >> 6;          // w in 0..7
    const int l15 = lane & 15, quad = lane >> 4;
    const int r0 = blockIdx.x * 16;
    const int c0w = w * 32;
    short8 wf[8][2];
#pragma unroll
    for (int kc = 0; kc < 8; ++kc)
#pragma unroll
        for (int dt = 0; dt < 2; ++dt)
            wf[kc][dt] = *(const short8*)(WT + (size_t)(c0w + dt * 16 + l15) * DD + kc * 32 + 8 * quad);
    float bv[2], gv[2], ev[2];
#pragma unroll
    for (int dt = 0; dt < 2; ++dt) {
        int col = c0w + dt * 16 + l15;
        bv[dt] = bias[col]; gv[dt] = g[col]; ev[dt] = be[col];
    }
    {   // stage A: 512 threads x 16B
        int row = tid >> 5, c0 = (tid & 31) * 8;
        *(short8*)(As + row * 264 + c0) = *(const short8*)(Ain + (size_t)(r0 + row) * DD + c0);
    }
    __syncthreads();
    fx4 acc[2];
#pragma unroll
    for (int i = 0; i < 2; ++i) acc[i] = (fx4){0.f, 0.f, 0.f, 0.f};
#pragma unroll
    for (int kc = 0; kc < 8; ++kc) {
        short8 a = *(const short8*)(As + l15 * 264 + kc * 32 + 8 * quad);
#pragma unroll
        for (int dt = 0; dt < 2; ++dt)
            acc[dt] = __builtin_amdgcn_mfma_f32_16x16x32_bf16(a, wf[kc][dt], acc[dt], 0, 0, 0);
    }
    float v[4][2], p1[4], p2[4];
#pragma unroll
    for (int r = 0; r < 4; ++r) {
        p1[r] = 0.f; p2[r] = 0.f;
        const size_t grow = r0 + 4 * quad + r;
#pragma unroll
        for (int dt = 0; dt < 2; ++dt) {
            float x = acc[dt][r] + bv[dt] + R[grow * DD + c0w + dt * 16 + l15];
            v[r][dt] = x; p1[r] += x; p2[r] += x * x;
        }
    }
#pragma unroll
    for (int r = 0; r < 4; ++r) {
#pragma unroll
        for (int off = 1; off <= 8; off <<= 1) {
            p1[r] += __shfl_xor(p1[r], off);
            p2[r] += __shfl_xor(p2[r], off);
        }
    }
    if (l15 == 0) {
#pragma unroll
        for (int r = 0; r < 4; ++r) {
            lnb[0][w][4 * quad + r] = p1[r];
            lnb[1][w][4 * quad + r] = p2[r];
        }
    }
    __syncthreads();
#pragma unroll
    for (int r = 0; r < 4; ++r) {
        const int row = 4 * quad + r;
        float s1 = 0.f, s2 = 0.f;
#pragma unroll
        for (int ww = 0; ww < 8; ++ww) { s1 += lnb[0][ww][row]; s2 += lnb[1][ww][row]; }
        float mean = s1 * (1.0f / 256.0f);
        float var  = s2 * (1.0f / 256.0f) - mean * mean;
        float rstd = rsqrtf(var + 1e-5f);
        const size_t grow = r0 + row;
#pragma unroll
        for (int dt = 0; dt < 2; ++dt)
            out[grow * DD + c0w + dt * 16 + l15] = (v[r][dt] - mean) * rstd * gv[dt] + ev[dt];
    }
}

// ---------------------------------------------------------------------------
// Flash attention, O^T form, no-max softmax (|s| <= ~2 by construction).
// Block = 32 q-rows, 4 waves: wave w -> q-subtile (w&1), K-half (w>>1).
// Per 32-key tile: S^T = K.Q^T (C col = q = l15) -> p = exp(s/8) per-thread
// -> pack -> XOR-swizzled LDS exchange -> od^T += V^T.P^T (od col = q).
// No shuffles, no barriers in loop. K-half merge = plain adds.
// ---------------------------------------------------------------------------
__global__ __launch_bounds__(256, 4) void attn_mfma(
        const unsigned short* __restrict__ Qp, const unsigned short* __restrict__ Kp,
        const unsigned short* __restrict__ VT, float* __restrict__ Opre) {
    __shared__ unsigned int pbuf[4][256];     // per-wave P exchange, pitch 16 dw
    __shared__ float macc[2][16][68];         // kh0 partial O^T [qs][q][d]
    __shared__ float lbuf[32];                // kh0 partial l    [qs*16+q]
    const int tid = threadIdx.x;
    const int lane = tid & 63, w = tid >> 6;
    const int l15 = lane & 15, quad = lane >> 4;
    const int qs = w & 1, kh = w >> 1;
    const int gb = blockIdx.x;
    const int bh = ((gb & 7) << 1) | ((gb >> 9) & 1);   // XCD-locality swizzle
    const int qc = (gb >> 3) & 63;
    const int h  = bh & 3;
    const int b  = bh >> 2;
    const int qrow = qc * 32 + qs * 16;
    const int sw = 4 * ((l15 >> 1) & 3);                // bank swizzle (per l15)

    short8 aq0, aq1;
    {
        const unsigned short* qptr = Qp + ((size_t)(b * NN + qrow + l15) * DD + h * DHH + 8 * quad);
        aq0 = *(const short8*)qptr;
        aq1 = *(const short8*)(qptr + 32);
    }
    fx4 od[4];
#pragma unroll
    for (int i = 0; i < 4; ++i) od[i] = (fx4){0.f, 0.f, 0.f, 0.f};
    float lsum = 0.0f;

    unsigned int* pw = &pbuf[w][0];
    const int wcol = (2 * quad) ^ sw;         // write cols (pairs t=2q,2q+1 / +8)
    const int rcol = (4 * quad) ^ sw;         // read col group (t=4Q..4Q+3)
    const unsigned short* kbase = Kp + ((size_t)(b * NN) * DD + h * DHH + 8 * quad);
    const unsigned short* vbase = VT + ((size_t)((b * HH + h) * DHH)) * NN + 8 * quad;

    auto pref = [&](short8* kf, short8* vf, int t) {
        const int kt = kh * 1024 + t * 32;
        const unsigned short* kp0 = kbase + (size_t)(kt + l15) * DD;
        kf[0] = *(const short8*)kp0;
        kf[1] = *(const short8*)(kp0 + 32);
        const unsigned short* kp1 = kbase + (size_t)(kt + 16 + l15) * DD;
        kf[2] = *(const short8*)kp1;
        kf[3] = *(const short8*)(kp1 + 32);
#pragma unroll
        for (int dt = 0; dt < 4; ++dt)
            vf[dt] = *(const short8*)(vbase + (size_t)(dt * 16 + l15) * NN + kt);
    };

    auto body = [&](short8* ck, short8* cv, short8* nk, short8* nv, int t) {
        const int tn = (t + 1 < 32) ? t + 1 : 31;
        pref(nk, nv, tn);                       // issue next-tile loads first
        const fx4 z = (fx4){0.f, 0.f, 0.f, 0.f};
        fx4 s0 = __builtin_amdgcn_mfma_f32_16x16x32_bf16(ck[0], aq0, z, 0, 0, 0);
        s0     = __builtin_amdgcn_mfma_f32_16x16x32_bf16(ck[1], aq1, s0, 0, 0, 0);
        fx4 s1 = __builtin_amdgcn_mfma_f32_16x16x32_bf16(ck[2], aq0, z, 0, 0, 0);
        s1     = __builtin_amdgcn_mfma_f32_16x16x32_bf16(ck[3], aq1, s1, 0, 0, 0);
#pragma unroll
        for (int i = 0; i < 4; ++i) {
            s0[i] = __expf(s0[i] * 0.125f);
            s1[i] = __expf(s1[i] * 0.125f);
            lsum += s0[i] + s1[i];
        }
        // pack p pairs (keys ascending) and exchange via swizzled LDS
        uint2v w1 = (uint2v){packbf(s0[0], s0[1]), packbf(s0[2], s0[3])};
        uint2v w2 = (uint2v){packbf(s1[0], s1[1]), packbf(s1[2], s1[3])};
        *(uint2v*)(pw + l15 * 16 + wcol)       = w1;   // pairs t=2q,2q+1
        *(uint2v*)(pw + l15 * 16 + (wcol ^ 8)) = w2;   // pairs t=8+2q,8+2q+1
        short8 bp = *(const short8*)(pw + l15 * 16 + rcol);  // keys 8*quad..+7
#pragma unroll
        for (int dt = 0; dt < 4; ++dt)
            od[dt] = __builtin_amdgcn_mfma_f32_16x16x32_bf16(cv[dt], bp, od[dt], 0, 0, 0);
    };

    short8 ka[4], va[4], kb[4], vb[4];
    pref(ka, va, 0);
    for (int tt = 0; tt < 16; ++tt) {
        body(ka, va, kb, vb, 2 * tt);
        body(kb, vb, ka, va, 2 * tt + 1);
    }
    // per-q total l for this wave (sum over quads)
    lsum += __shfl_xor(lsum, 16);
    lsum += __shfl_xor(lsum, 32);
    // ---- merge the two K-halves (plain adds; no max state) ----
    if (kh == 0) {
#pragma unroll
        for (int dt = 0; dt < 4; ++dt)
            *(fx4*)&macc[qs][l15][dt * 16 + 4 * quad] = od[dt];
        if (quad == 0) lbuf[qs * 16 + l15] = lsum;
    }
    __syncthreads();
    if (kh == 1) {
        const float inv = 1.0f / (lsum + lbuf[qs * 16 + l15]);
        const size_t grow = (size_t)(b * NN) + qrow + l15;
        float* obase = Opre + grow * DD + h * DHH;
        const unsigned short* qpb = Qp + grow * DD + h * DHH;
#pragma unroll
        for (int dt = 0; dt < 4; ++dt) {
            fx4 mv = *(const fx4*)&macc[qs][l15][dt * 16 + 4 * quad];
            shortx4 rv = *(const shortx4*)(qpb + dt * 16 + 4 * quad);
            fx4 o;
#pragma unroll
            for (int i = 0; i < 4; ++i)
                o[i] = (od[dt][i] + mv[i]) * inv + bf2f((unsigned short)rv[i]);
            *(fx4*)(obase + dt * 16 + 4 * quad) = o;
        }
    }
}

// row LayerNorm: Y = LN(X)*g+be (fp32)
__global__ __launch_bounds__(64) void ln_rows(
        const float* __restrict__ X, const float* __restrict__ g,
        const float* __restrict__ be, float* __restrict__ Y) {
    const int lane = threadIdx.x;
    const size_t row = blockIdx.x;
    fx4 v = ((const fx4*)(X + row * DD))[lane];
    float s1 = v[0]+v[1]+v[2]+v[3];
    float s2 = v[0]*v[0]+v[1]*v[1]+v[2]*v[2]+v[3]*v[3];
#pragma unroll
    for (int off = 32; off >= 1; off >>= 1) {
        s1 += __shfl_xor(s1, off); s2 += __shfl_xor(s2, off);
    }
    float mean = s1 * (1.0f/256.0f);
    float var  = s2 * (1.0f/256.0f) - mean * mean;
    float rstd = rsqrtf(var + 1e-5f);
    fx4 gv = ((const fx4*)g)[lane];
    fx4 ev = ((const fx4*)be)[lane];
    fx4 o;
#pragma unroll
    for (int i = 0; i < 4; ++i) o[i] = (v[i]-mean)*rstd*gv[i] + ev[i];
    ((fx4*)(Y + row * DD))[lane] = o;
}

extern "C" void kernel_launch(void* const* d_in, const int* in_sizes, int n_in,
                              void* d_out, int out_size, void* d_ws, size_t ws_size,
                              hipStream_t stream) {
    (void)in_sizes; (void)n_in; (void)out_size; (void)ws_size;
    const float* Q     = (const float*)d_in[0];
    const float* K     = (const float*)d_in[1];
    const float* Wq    = (const float*)d_in[2];
    const float* bq    = (const float*)d_in[3];
    const float* Wk    = (const float*)d_in[4];
    const float* bk    = (const float*)d_in[5];
    const float* Wv    = (const float*)d_in[6];
    const float* bv    = (const float*)d_in[7];
    const float* W1    = (const float*)d_in[8];
    const float* b1    = (const float*)d_in[9];
    const float* W2    = (const float*)d_in[10];
    const float* b2    = (const float*)d_in[11];
    const float* g0    = (const float*)d_in[12];
    const float* beta0 = (const float*)d_in[13];
    const float* g1    = (const float*)d_in[14];
    const float* beta1 = (const float*)d_in[15];

    // Workspace: [0,4)Mi Qp bf16 (later H1 bf16); [4,8)Mi Kp; [8,12)Mi Vp;
    // [12,16)Mi VT; [16,24)Mi Opre f32; [24,32)Mi O f32; [32Mi,+640K) WT x5
    char* ws = (char*)d_ws;
    unsigned short* Qp  = (unsigned short*)(ws);
    unsigned short* Kp  = (unsigned short*)(ws + (4u  << 20));
    unsigned short* Vp  = (unsigned short*)(ws + (8u  << 20));
    unsigned short* VT  = (unsigned short*)(ws + (12u << 20));
    float*          Opre= (float*)(ws + (16u << 20));
    float*          O   = (float*)(ws + (24u << 20));
    unsigned short* WT5 = (unsigned short*)(ws + (32u << 20));
    unsigned short* H1  = Qp;
    float*          out = (float*)d_out;

    const unsigned short* WT1 = WT5 + 3 * 65536;
    const unsigned short* WT2 = WT5 + 4 * 65536;

    const int M = BB * NN;                        // 8192 rows

    wt_prep<<<dim3(4, 4, 5), 256, 0, stream>>>(Wq, Wk, Wv, W1, W2, WT5);
    qkv_mfma<<<dim3(M / 16, 3), 256, 0, stream>>>(Q, K, WT5, bq, bk, bv, Qp, Kp, Vp);
    vt_prep<<<dim3(128, 4), 256, 0, stream>>>(Vp, VT);
    attn_mfma<<<BB * HH * (NN / 32), 256, 0, stream>>>(Qp, Kp, VT, Opre);
    ln_rows<<<M, 64, 0, stream>>>(Opre, g0, beta0, O);
    ffn1_mfma<<<M / 16, 256, 0, stream>>>(O, WT1, b1, H1);
    gemm_ffn2_ln<<<M / 16, 512, 0, stream>>>(H1, WT2, b2, O, g1, beta1, out);
}